// Round 8
// baseline (253.663 us; speedup 1.0000x reference)
//
#include <hip/hip_runtime.h>
#include <math.h>

#define VV 128000
#define NB 128
#define PP 2048
#define OO 256
#define GW 4000        // VV/32 words per row mask

#define S    20        // chunks per row
#define CH   6400      // tokens per chunk
#define CW   200       // CH/32 mask words
#define NSLAB 25       // CH/256 (1 KB slabs)
#define NRUN (S + 1)   // 20 chunk runs + 1 penalized run

#define NT0 512
#define NT1 512
#define NT2 256
#define CAP 512        // survivor slots
#define HS1 512        // hash slots
#define PCAP 2560      // penalized-token key capacity (max ~2308)

#define BIG_NEG_F (-1e30f)
#define PAD_KEY 0x007FFFFF80000000ULL  // packkey(-inf, 0x7fffffff)
#define LOG2E 1.4426950408889634f

#define AS1(p) ((__attribute__((address_space(1))) void*)(p))
#define AS3(p) ((__attribute__((address_space(3))) void*)(p))

__device__ __forceinline__ unsigned long long packkey(float f, int idx) {
  unsigned int b = __float_as_uint(f);
  unsigned int mf = (b & 0x80000000u) ? ~b : (b | 0x80000000u);
  return ((unsigned long long)mf << 32) | (unsigned long long)(unsigned int)(~(unsigned int)idx);
}
__device__ __forceinline__ float unpack_val(unsigned long long k) {
  unsigned int mf = (unsigned int)(k >> 32);
  unsigned int b = (mf & 0x80000000u) ? (mf & 0x7fffffffu) : ~mf;
  return __uint_as_float(b);
}
__device__ __forceinline__ int unpack_idx(unsigned long long k) {
  return (int)(~(unsigned int)(k & 0xffffffffu));
}

// in-register descending bitonic sort across a wave (lane L -> (L+1)-th largest)
__device__ __forceinline__ float wave_sort64_desc(float v, int lane) {
  for (int k = 2; k <= 64; k <<= 1) {
    for (int j = k >> 1; j > 0; j >>= 1) {
      float o = __shfl_xor(v, j, 64);
      bool smaller = (lane & j) == 0;
      bool dir = (lane & k) == 0;
      v = (smaller == dir) ? fmaxf(v, o) : fminf(v, o);
    }
  }
  return v;
}
__device__ __forceinline__ unsigned long long wave_sort64_desc_u64(unsigned long long v, int lane) {
  for (int k = 2; k <= 64; k <<= 1) {
    for (int j = k >> 1; j > 0; j >>= 1) {
      unsigned long long o = __shfl_xor(v, j, 64);
      bool smaller = (lane & j) == 0;
      bool dir = (lane & k) == 0;
      unsigned long long mx = (v > o) ? v : o;
      unsigned long long mn = (v > o) ? o : v;
      v = (smaller == dir) ? mx : mn;
    }
  }
  return v;
}
// merge two sorted-desc 64-runs (v = own run, B = other run in LDS), keep top-64 sorted.
__device__ __forceinline__ unsigned long long merge_top64(unsigned long long v,
                                                          const unsigned long long* B,
                                                          int lane) {
  unsigned long long b = B[63 - lane];
  v = (v > b) ? v : b;
  for (int j = 32; j > 0; j >>= 1) {
    unsigned long long o = __shfl_xor(v, j, 64);
    bool hi = (lane & j) == 0;
    unsigned long long mx = (v > o) ? v : o;
    unsigned long long mn = (v > o) ? o : v;
    v = hi ? mx : mn;
  }
  return v;
}

// ---- kernel 0: merged mask + exact penalized-token run (sorted top-64 + Z) ----
__global__ __launch_bounds__(NT0)
void k0_build(const float* __restrict__ logits,
              const int* __restrict__ prompt_ids,
              const int* __restrict__ output_ids,
              const int* __restrict__ stop_ids,
              const int* __restrict__ min_tokens,
              const float* __restrict__ presence_p,
              const float* __restrict__ frequency_p,
              const float* __restrict__ repetition_p,
              const float* __restrict__ temperature,
              unsigned int* __restrict__ ws_mb,
              unsigned long long* __restrict__ ws_top,
              float* __restrict__ ws_sum)
{
#pragma clang fp contract(off)
  __shared__ unsigned int pobits[GW];                    // prompt|output bits
  __shared__ int hkey[HS1];
  __shared__ int hval[HS1];
  __shared__ __align__(16) unsigned long long penk[PCAP];
  __shared__ unsigned long long cand[CAP];
  __shared__ float wtau[NT0 / 64];
  __shared__ float wsum[NT0 / 64];
  __shared__ float tau_sh;
  __shared__ int pcnt_sh, cnt_sh;

  const int row = blockIdx.x;
  const int tid = threadIdx.x;
  const int lane = tid & 63;
  const int wv = tid >> 6;

  const float fp = frequency_p[row];
  const float pp = presence_p[row];
  const float rp = repetition_p[row];
  const float tmp = temperature[row];
  const float t = (tmp < 1e-5f) ? 1.0f : tmp;
  const bool need = min_tokens[row] > OO;
  const int s0 = stop_ids[row * 4 + 0], s1 = stop_ids[row * 4 + 1],
            s2 = stop_ids[row * 4 + 2], s3 = stop_ids[row * 4 + 3];

  { uint4 z; z.x = z.y = z.z = z.w = 0u;
    uint4* pb4 = (uint4*)pobits;
    for (int i = tid; i < GW / 4; i += NT0) pb4[i] = z; }
  for (int i = tid; i < HS1; i += NT0) { hkey[i] = -1; hval[i] = 0; }
  if (tid == 0) { pcnt_sh = 0; cnt_sh = 0; }
  __syncthreads();

  { const int4* pr4 = (const int4*)(prompt_ids + (size_t)row * PP);
    for (int i = tid; i < PP / 4; i += NT0) {
      int4 tv = pr4[i];
      atomicOr(&pobits[tv.x >> 5], 1u << (tv.x & 31));
      atomicOr(&pobits[tv.y >> 5], 1u << (tv.y & 31));
      atomicOr(&pobits[tv.z >> 5], 1u << (tv.z & 31));
      atomicOr(&pobits[tv.w >> 5], 1u << (tv.w & 31));
    } }
  for (int i = tid; i < OO; i += NT0) {
    int tok = output_ids[row * OO + i];
    atomicOr(&pobits[tok >> 5], 1u << (tok & 31));
    unsigned int h = ((unsigned int)tok * 2654435761u) >> 23;
    for (;;) {
      int k = hkey[h];
      if (k == tok) { atomicAdd(&hval[h], 1); break; }
      if (k == -1) {
        int prev = atomicCAS(&hkey[h], -1, tok);
        if (prev == -1 || prev == tok) { atomicAdd(&hval[h], 1); break; }
        continue;
      }
      h = (h + 1) & (HS1 - 1);
    }
  }
  __syncthreads();

  // copy-out merged mask + exact penalized values (reference op order)
  float penmax = -INFINITY;
  float esum = 0.0f;
  for (int w = tid; w < GW; w += NT0) {
    unsigned pb = pobits[w];
    unsigned sw = 0u;
    if (need) {
      if ((s0 >> 5) == w) sw |= 1u << (s0 & 31);
      if ((s1 >> 5) == w) sw |= 1u << (s1 & 31);
      if ((s2 >> 5) == w) sw |= 1u << (s2 & 31);
      if ((s3 >> 5) == w) sw |= 1u << (s3 & 31);
    }
    unsigned mw = pb | sw;
    ws_mb[(size_t)row * GW + w] = mw;
    while (mw) {
      int b = __ffs(mw) - 1;
      mw &= mw - 1;
      int tok = (w << 5) + b;
      float x = logits[(size_t)row * VV + tok];
      if (need && (tok == s0 || tok == s1 || tok == s2 || tok == s3))
        x = fminf(x, BIG_NEG_F);
      bool pmom = (pb >> b) & 1u;     // in prompt-or-output set
      float cnt = 0.0f;
      { unsigned int h = ((unsigned int)tok * 2654435761u) >> 23;
        for (;;) {
          int k = hkey[h];
          if (k == -1) break;
          if (k == tok) { cnt = (float)hval[h]; break; }
          h = (h + 1) & (HS1 - 1);
        } }
      bool om = cnt > 0.0f;
      if (pmom) x = (x > 0.0f) ? (x / rp) : (x * rp);
      x = x - fp * cnt;
      if (om) x = x - pp;
      float xd = x / t;
      esum += exp2f(xd * LOG2E);
      penmax = fmaxf(penmax, xd);
      int p = atomicAdd(&pcnt_sh, 1);
      if (p < PCAP) penk[p] = packkey(xd, tok);
    }
  }

  float ssr = esum;
  for (int off = 32; off > 0; off >>= 1) ssr += __shfl_down(ssr, off, 64);
  if (lane == 0) wsum[wv] = ssr;
  float srt = wave_sort64_desc(penmax, lane);
  if (lane == 7) wtau[wv] = srt;
  __syncthreads();
  if (tid == 0) {
    float tau = wtau[0];
    for (int w2 = 1; w2 < NT0 / 64; ++w2) tau = fminf(tau, wtau[w2]);
    tau_sh = tau;
    float sa = 0.0f;
    for (int w2 = 0; w2 < NT0 / 64; ++w2) sa += wsum[w2];
    ws_sum[row * NRUN + S] = sa;
  }
  __syncthreads();

  const unsigned long long thr = packkey(tau_sh, 0x7fffffff);
  int np = pcnt_sh; if (np > PCAP) np = PCAP;
  for (int i = tid; i < np; i += NT0) {
    unsigned long long k = penk[i];
    if (k >= thr) { int p = atomicAdd(&cnt_sh, 1); if (p < CAP) cand[p] = k; }
  }
  __syncthreads();
  int total = cnt_sh; if (total > CAP) total = CAP;
  for (int i = tid; i < CAP; i += NT0) if (i >= total) cand[i] = PAD_KEY;
  __syncthreads();
  unsigned long long rv = wave_sort64_desc_u64(cand[(wv << 6) + lane], lane);
  cand[(wv << 6) + lane] = rv;
  __syncthreads();
  unsigned long long* mb = penk;   // scratch alias (penk dead)
  if (wv < 4) {
    unsigned long long a = cand[((2 * wv) << 6) + lane];
    a = merge_top64(a, &cand[(2 * wv + 1) << 6], lane);
    mb[(wv << 6) + lane] = a;
  }
  __syncthreads();
  if (wv < 2) {
    unsigned long long a = mb[((2 * wv) << 6) + lane];
    a = merge_top64(a, &mb[(2 * wv + 1) << 6], lane);
    cand[(wv << 6) + lane] = a;
  }
  __syncthreads();
  if (wv == 0) {
    unsigned long long a = cand[lane];
    a = merge_top64(a, &cand[64], lane);
    ws_top[((size_t)row * NRUN + S) * 64 + lane] = a;
  }
}

// ---- kernel 1: LDS-staged branchless scan + exact top-64 of non-masked -----
__global__ __launch_bounds__(NT1)
void k1_select(const float* __restrict__ logits,
               const float* __restrict__ temperature,
               const unsigned int* __restrict__ ws_mb,
               unsigned long long* __restrict__ ws_top,
               float* __restrict__ ws_sum)
{
  __shared__ __align__(16) float chbuf[CH];       // 25.6 KB staged chunk
  __shared__ unsigned int mbits[CW];
  __shared__ unsigned long long cand[CAP];
  __shared__ float wtau[NT1 / 64];
  __shared__ float wsum[NT1 / 64];
  __shared__ float tau_sh;
  __shared__ int cnt_sh;

  const int ck  = blockIdx.x;
  const int row = blockIdx.y;
  const int tid = threadIdx.x;
  const int lane = tid & 63;
  const int wv = tid >> 6;
  const int base = ck * CH;

  const float tmp = temperature[row];
  const float t = (tmp < 1e-5f) ? 1.0f : tmp;
  const float c2 = LOG2E / t;

  // async stage: 25 slabs of 1 KB, VGPR-free, all in flight
  const float* lrow = logits + (size_t)row * VV + base;
  for (int slab = wv; slab < NSLAB; slab += NT1 / 64) {
    __builtin_amdgcn_global_load_lds(AS1(lrow + (slab << 8) + (lane << 2)),
                                     AS3(chbuf + (slab << 8)), 16, 0, 0);
  }
  { const uint4* src = (const uint4*)(ws_mb + (size_t)row * GW + ck * CW);
    if (tid < CW / 4) ((uint4*)mbits)[tid] = src[tid]; }
  if (tid == 0) cnt_sh = 0;
  __syncthreads();                                 // drains staging + barrier

  // phase A: branchless max + exp2-sum over non-masked (masked -> -inf)
  float mx = -INFINITY;
  float esum = 0.0f;
  const float4* ch4 = (const float4*)chbuf;
#pragma unroll
  for (int it = 0; it < 4; ++it) {
    int i4 = it * NT1 + tid;
    if (i4 < CH / 4) {
      float4 xv = ch4[i4];
      unsigned mw = mbits[i4 >> 3];
      unsigned m4 = (mw >> ((i4 & 7) << 2)) & 15u;
#pragma unroll
      for (int e = 0; e < 4; ++e) {
        float x = (&xv.x)[e];
        float xm = (m4 & (1u << e)) ? -INFINITY : x;
        mx = fmaxf(mx, xm);
        esum += exp2f(xm * c2);
      }
    }
  }

  float ssr = esum;
  for (int off = 32; off > 0; off >>= 1) ssr += __shfl_down(ssr, off, 64);
  if (lane == 0) wsum[wv] = ssr;
  float srt = wave_sort64_desc(mx, lane);
  if (lane == 7) wtau[wv] = srt;                   // wave's 8th-largest
  __syncthreads();
  if (tid == 0) {
    float tau = wtau[0];
    for (int w = 1; w < NT1 / 64; ++w) tau = fminf(tau, wtau[w]);
    tau_sh = tau;                                  // exact: no slack needed
    float sa = 0.0f;
    for (int w = 0; w < NT1 / 64; ++w) sa += wsum[w];
    ws_sum[row * NRUN + ck] = sa;
  }
  __syncthreads();
  const float taueff = tau_sh;

  // phase B: filter from LDS, append survivors (non-masked raw >= tau)
#pragma unroll
  for (int it = 0; it < 4; ++it) {
    int i4 = it * NT1 + tid;
    if (i4 < CH / 4) {
      float4 xv = ch4[i4];
      unsigned mw = mbits[i4 >> 3];
      unsigned m4 = (mw >> ((i4 & 7) << 2)) & 15u;
#pragma unroll
      for (int e = 0; e < 4; ++e) {
        float x = (&xv.x)[e];
        if (x >= taueff && !(m4 & (1u << e))) {
          int p = atomicAdd(&cnt_sh, 1);
          if (p < CAP) cand[p] = packkey(x / t, base + (i4 << 2) + e);
        }
      }
    }
  }
  __syncthreads();
  int total = cnt_sh; if (total > CAP) total = CAP;
  for (int i = tid; i < CAP; i += NT1) if (i >= total) cand[i] = PAD_KEY;
  __syncthreads();

  // exact sorted top-64: 8 register-sorted runs + tournament
  unsigned long long rv = wave_sort64_desc_u64(cand[(wv << 6) + lane], lane);
  cand[(wv << 6) + lane] = rv;
  __syncthreads();
  unsigned long long* mb = (unsigned long long*)chbuf;  // chunk dead: alias
  if (wv < 4) {
    unsigned long long a = cand[((2 * wv) << 6) + lane];
    a = merge_top64(a, &cand[(2 * wv + 1) << 6], lane);
    mb[(wv << 6) + lane] = a;
  }
  __syncthreads();
  if (wv < 2) {
    unsigned long long a = mb[((2 * wv) << 6) + lane];
    a = merge_top64(a, &mb[(2 * wv + 1) << 6], lane);
    cand[(wv << 6) + lane] = a;
  }
  __syncthreads();
  if (wv == 0) {
    unsigned long long a = cand[lane];
    a = merge_top64(a, &cand[64], lane);
    ws_top[((size_t)row * NRUN + ck) * 64 + lane] = a;
  }
}

// ---- kernel 2: tournament-merge 21 runs + finalize -------------------------
__global__ __launch_bounds__(NT2)
void k2_finalize(const float* __restrict__ temperature,
                 const int* __restrict__ top_k,
                 const float* __restrict__ top_p,
                 const float* __restrict__ noise,
                 const unsigned long long* __restrict__ ws_top,
                 const float* __restrict__ ws_sum,
                 float* __restrict__ out, int K)
{
#pragma clang fp contract(off)
  __shared__ unsigned long long runs[32 * 64];
  __shared__ unsigned long long scr[16 * 64];
  __shared__ float sv[64];
  __shared__ int   si[64];
  __shared__ float se[64];
  __shared__ float gv[64];

  const int row = blockIdx.x;
  const int tid = threadIdx.x;
  const int lane = tid & 63;
  const int wv = tid >> 6;        // 4 waves

  const float tmp = temperature[row];
  const float t = (tmp < 1e-5f) ? 1.0f : tmp;
  const int tk = top_k[row];
  const float tpv = top_p[row];

  for (int i = tid; i < 32 * 64; i += NT2) {
    int r = i >> 6;
    runs[i] = (r < NRUN) ? ws_top[((size_t)row * NRUN + r) * 64 + (i & 63)]
                         : PAD_KEY;
  }
  __syncthreads();

  unsigned long long* p = runs;
  unsigned long long* q = scr;
  for (int nout = 16; nout >= 1; nout >>= 1) {
    for (int m = wv; m < nout; m += 4) {
      unsigned long long a = p[((2 * m) << 6) + lane];
      a = merge_top64(a, &p[((2 * m + 1) << 6)], lane);
      q[(m << 6) + lane] = a;
    }
    __syncthreads();
    unsigned long long* tp = p; p = q; q = tp;
  }
  // p[0..63] = final sorted top-64
  if (wv == 0) {
    unsigned long long a = p[lane];
    float val = unpack_val(a);
    int idx = unpack_idx(a);
    float m = __shfl(val, 0, 64);
    sv[lane] = val;
    si[lane] = idx;
    bool ok = (unsigned)idx < VV;
    float u = ok ? noise[(size_t)row * VV + idx] : 0.5f;
    float g = -logf(-logf(u));
    se[lane] = expf(val - m);
    gv[lane] = val / t + g;
  }
  __syncthreads();

  if (tid == 0) {
    float Ssum = 0.0f;
    for (int c = 0; c < NRUN; c++) Ssum += ws_sum[row * NRUN + c];
    const float m = sv[0];
    const float Z = Ssum * exp2f(-m * LOG2E);   // full-row softmax denominator

    int keff = (tk < 1) ? 64 : (tk < 64 ? tk : 64);

    float cum = 0.0f;
    int nk = 0;
    for (int j = 0; j < 64; j++) {
      if (j >= keff) break;
      if (!(cum < tpv)) break;
      nk++;
      cum += se[j] / Z;
    }

    float Zk = 0.0f;
    for (int j = 0; j < nk; j++) Zk += se[j];
    const float logZk = logf(Zk);

    float bv = -INFINITY; int bi = 0x7fffffff;
    for (int j = 0; j < nk; j++) {
      float val = gv[j];
      if (val > bv || (val == bv && si[j] < bi)) { bv = val; bi = si[j]; }
    }
    const int samp = (tmp < 1e-5f) ? si[0] : bi;
    out[row] = (float)samp;

    unsigned long long bm0 = 0ull, bm1 = 0ull;
    for (int j = 0; j < nk; j++) {
      int ix = si[j];
      if (ix < 64) bm0 |= 1ull << ix;
      else if (ix < 128) bm1 |= 1ull << (ix - 64);
    }
    int fi = 0;
    for (int j = 0; j < K; j++) {
      float lp; int ix;
      if (j < nk) {
        lp = (sv[j] - m) - logZk;
        ix = si[j];
      } else {
        while ((fi < 64) ? ((bm0 >> fi) & 1ull) : ((bm1 >> (fi - 64)) & 1ull)) fi++;
        ix = fi; fi++;
        lp = BIG_NEG_F;
      }
      out[NB + row * K + j]            = lp;
      out[NB + NB * K + row * K + j]   = (float)ix;
    }
  }
}

extern "C" void kernel_launch(void* const* d_in, const int* in_sizes, int n_in,
                              void* d_out, int out_size, void* d_ws, size_t ws_size,
                              hipStream_t stream) {
  const float* logits = (const float*)d_in[0];
  const int*   prompt = (const int*)d_in[1];
  const int*   outids = (const int*)d_in[2];
  const int*   stop   = (const int*)d_in[3];
  const int*   mint   = (const int*)d_in[4];
  const float* pres   = (const float*)d_in[5];
  const float* freq   = (const float*)d_in[6];
  const float* rep    = (const float*)d_in[7];
  const float* temp   = (const float*)d_in[8];
  const int*   topk   = (const int*)d_in[9];
  const float* topp   = (const float*)d_in[10];
  const float* noise  = (const float*)d_in[11];

  int B_ = in_sizes[4];                     // 128
  int K_ = (out_size - B_) / (2 * B_);      // 20

  unsigned long long* ws_top = (unsigned long long*)d_ws;   // NB*NRUN*64 u64
  unsigned int* ws_mb = (unsigned int*)(ws_top + (size_t)NB * NRUN * 64);
  float* ws_sum = (float*)(ws_mb + (size_t)NB * GW);

  k0_build<<<B_, NT0, 0, stream>>>(logits, prompt, outids, stop, mint,
                                   pres, freq, rep, temp,
                                   ws_mb, ws_top, ws_sum);
  dim3 g1(S, B_);
  k1_select<<<g1, NT1, 0, stream>>>(logits, temp, ws_mb, ws_top, ws_sum);
  k2_finalize<<<B_, NT2, 0, stream>>>(temp, topk, topp, noise,
                                      ws_top, ws_sum, (float*)d_out, K_);
}